// Round 8
// baseline (494.254 us; speedup 1.0000x reference)
//
#include <hip/hip_runtime.h>
#include <hip/hip_bf16.h>
#include <cstdint>

#define BATCH 16
#define TTOT  4096
#define DIN   512
#define DOUT  512
#define NG    8
#define NJB   18     // m-jobs per batch at BM=256
#define NKT   16     // K tiles of 32

typedef float f32x4 __attribute__((ext_vector_type(4)));
typedef short s16x8 __attribute__((ext_vector_type(8)));

__device__ __forceinline__ short f2b(float f) {
    union { __bf16 b; short s; } u; u.b = (__bf16)f; return u.s;
}

// M-job tables (BM=256): (t0, group, valid_rows) per batch. (verified R7)
__device__ __constant__ short JT0[NJB] = {
    0,256,512,768,1024,1280,1536,1792,1920,2176,2432,2560,2816,3072,3328,3584,3648,3904};
__device__ __constant__ char JG[NJB] = {
    0,1,1,2,2,2,3,3,4,4,4,5,5,6,6,6,7,7};
__device__ __constant__ short JVR[NJB] = {
    256,256,256,256,256,256,256,128,256,256,128,256,256,256,256,64,256,192};

// ---- Kernel 1: W fp32 -> bf16 LDS-image chunks (NO swizzle; BK=32) ----
// chunk c = (g*2+nt)*16+kt (16KB): image[row<256][bc<64 bytes] =
//   bf16 W[g][nt*256+row][kt*32 + bc/2]
__global__ void wconv_kernel(const float* __restrict__ W, ushort* __restrict__ wbf) {
    int gid = blockIdx.x * 256 + threadIdx.x;   // 262144 granules x 16B
    int c = gid >> 10;                          // 0..255
    int q = (gid & 1023) << 4;                  // byte in chunk
    int row = q >> 6;                           // 0..255
    int bc  = q & 63;
    int kt = c & 15, nt = (c >> 4) & 1, g = c >> 5;
    const float* wp = W + ((size_t)((g << 9) + (nt << 8) + row) << 9)
                        + (kt << 5) + (bc >> 1);
    float4 v0 = *reinterpret_cast<const float4*>(wp);
    float4 v1 = *reinterpret_cast<const float4*>(wp + 4);
    s16x8 o;
    o[0]=f2b(v0.x); o[1]=f2b(v0.y); o[2]=f2b(v0.z); o[3]=f2b(v0.w);
    o[4]=f2b(v1.x); o[5]=f2b(v1.y); o[6]=f2b(v1.z); o[7]=f2b(v1.w);
    *reinterpret_cast<s16x8*>((char*)wbf + (size_t)c * 16384 + q) = o;
}

// ---- Kernel 2: grouped GEMM 256x256x32, 8 waves (2Mx4N), wave-tile 128x64.
// LDS 64KB/block -> 2 blocks/CU (16 waves/CU). A reg-staged fp32->bf16 dbuf,
// B global_load_lds dbuf, counted vmcnt(4): A(kt+2) rides every barrier. ----
__launch_bounds__(512, 4)
__global__ void gemm_kernel(const float* __restrict__ x,
                            const ushort* __restrict__ wbf,
                            const float* __restrict__ bias,
                            float* __restrict__ out) {
    // [A0 16K][A1 16K][B0 16K][B1 16K]; epilogue C-tile overlays (33.3K)
    __shared__ __align__(16) char smem[65536];

    const int tid  = threadIdx.x;
    const int lane = tid & 63;
    const int wv   = tid >> 6;      // 0..7
    const int wm   = wv >> 2;       // 0..1 : 128-row slab
    const int wn   = wv & 3;        // 0..3 : 64-col slab
    const int colf = lane & 15;
    const int kg   = lane >> 4;

    const int p    = blockIdx.x;                 // 0..575
    const int l    = (p & 7) * 72 + (p >> 3);    // XCD-chunked (576 = 8*72)
    const int nt   = l & 1;                      // nt-siblings adjacent, same XCD
    const int rest = l >> 1;                     // 0..287
    const int batch = rest / NJB;
    const int j     = rest - batch * NJB;
    const int t0    = JT0[j];
    const int g     = JG[j];
    const int vr    = JVR[j];
    const int n0    = nt << 8;

    const char* bchunk = (const char*)wbf + (size_t)(((g << 1) + nt) << 4) * 16384;

    // A staging: thread -> row r = tid>>1 (0..255), half h = tid&1 (16 f32)
    const int r = tid >> 1;
    const int h = tid & 1;
    const int re = (r < vr) ? r : (vr - 1);      // clamp stub rows
    const float* arow_ptr = x + (((size_t)(batch * TTOT + t0 + re)) << 9) + (h << 4);

    float4 st0[4], st1[4];   // 2-deep staging regs (parity)

#define ISSUE_A(S, KT_) do {                                                \
        const float* p_ = arow_ptr + ((KT_) << 5);                          \
        st##S[0] = *(const float4*)(p_);                                    \
        st##S[1] = *(const float4*)(p_ + 4);                                \
        st##S[2] = *(const float4*)(p_ + 8);                                \
        st##S[3] = *(const float4*)(p_ + 12);                               \
    } while (0)

#define CVT_WRITE_A(S, KT_) do {                                            \
        char* ab_ = smem + ((KT_) & 1) * 16384;                             \
        s16x8 o0_, o1_;                                                     \
        o0_[0]=f2b(st##S[0].x); o0_[1]=f2b(st##S[0].y);                     \
        o0_[2]=f2b(st##S[0].z); o0_[3]=f2b(st##S[0].w);                     \
        o0_[4]=f2b(st##S[1].x); o0_[5]=f2b(st##S[1].y);                     \
        o0_[6]=f2b(st##S[1].z); o0_[7]=f2b(st##S[1].w);                     \
        o1_[0]=f2b(st##S[2].x); o1_[1]=f2b(st##S[2].y);                     \
        o1_[2]=f2b(st##S[2].z); o1_[3]=f2b(st##S[2].w);                     \
        o1_[4]=f2b(st##S[3].x); o1_[5]=f2b(st##S[3].y);                     \
        o1_[6]=f2b(st##S[3].z); o1_[7]=f2b(st##S[3].w);                     \
        *(s16x8*)(ab_ + (r << 6) + (h << 5))      = o0_;                    \
        *(s16x8*)(ab_ + (r << 6) + (h << 5) + 16) = o1_;                    \
    } while (0)

#define ISSUE_B(KT_) do {                                                   \
        const char* src_ = bchunk + (size_t)(KT_) * 16384 + tid * 16;       \
        char* dst_ = smem + 32768 + ((KT_) & 1) * 16384 + tid * 16;         \
        __builtin_amdgcn_global_load_lds(                                   \
            (const __attribute__((address_space(1))) void*)(src_),          \
            (__attribute__((address_space(3))) void*)(dst_), 16, 0, 0);     \
        __builtin_amdgcn_global_load_lds(                                   \
            (const __attribute__((address_space(1))) void*)(src_ + 8192),   \
            (__attribute__((address_space(3))) void*)(dst_ + 8192), 16, 0, 0);\
    } while (0)

#define COMPUTE(KT_) do {                                                   \
        const char* ab_ = smem + ((KT_) & 1) * 16384;                       \
        const char* bb_ = smem + 32768 + ((KT_) & 1) * 16384;               \
        __builtin_amdgcn_s_setprio(1);                                      \
        s16x8 bf[4];                                                        \
        _Pragma("unroll")                                                   \
        for (int ni = 0; ni < 4; ++ni)                                      \
            bf[ni] = *(const s16x8*)(bb_ + ((wn * 64 + ni * 16 + colf) << 6)\
                                     + (kg << 4));                          \
        _Pragma("unroll")                                                   \
        for (int mi = 0; mi < 8; ++mi) {                                    \
            s16x8 af = *(const s16x8*)(ab_ + ((wm * 128 + mi * 16 + colf) << 6) \
                                       + (kg << 4));                        \
            _Pragma("unroll")                                               \
            for (int ni = 0; ni < 4; ++ni)                                  \
                acc[mi][ni] = __builtin_amdgcn_mfma_f32_16x16x32_bf16(      \
                    af, bf[ni], acc[mi][ni], 0, 0, 0);                      \
        }                                                                   \
        __builtin_amdgcn_s_setprio(0);                                      \
    } while (0)

#define FENCE  asm volatile("" ::: "memory")
#define WAITV4 asm volatile("s_waitcnt vmcnt(4)" ::: "memory")
#define WAITV0 asm volatile("s_waitcnt vmcnt(0)" ::: "memory")
#define WAITL0 asm volatile("s_waitcnt lgkmcnt(0)" ::: "memory")
#define BARRIER do { FENCE; __builtin_amdgcn_s_barrier(); FENCE; } while (0)

    f32x4 acc[8][4];
#pragma unroll
    for (int mi = 0; mi < 8; ++mi)
#pragma unroll
        for (int ni = 0; ni < 4; ++ni)
            acc[mi][ni] = (f32x4){0.f, 0.f, 0.f, 0.f};

    // ---- prologue ----
    ISSUE_B(0);
    ISSUE_A(0, 0);       // st0 = A(0)
    ISSUE_A(1, 1);       // st1 = A(1)
    FENCE;
    CVT_WRITE_A(0, 0);   // compiler waits A(0) (drains B(0) too), writes A_lds[0]
    WAITL0;
    BARRIER;

#pragma unroll
    for (int kt = 0; kt < NKT; ++kt) {
        if (kt + 1 < NKT) { ISSUE_B(kt + 1); }
        if (kt + 2 < NKT) {
            if (((kt + 2) & 1) == 0) { ISSUE_A(0, kt + 2); }
            else                     { ISSUE_A(1, kt + 2); }
        }
        FENCE;
        COMPUTE(kt);
        if (kt + 1 < NKT) {
            if (((kt + 1) & 1) == 0) { CVT_WRITE_A(0, kt + 1); }
            else                     { CVT_WRITE_A(1, kt + 1); }
            if (kt + 2 < NKT) { WAITV4; }   // drain B(kt+1); A(kt+2) rides
            else              { WAITV0; }   // kt==14: only B(15) outstanding
            WAITL0;
            BARRIER;
        }
    }

    WAITL0;
    BARRIER;   // all LDS reads done before C overlay

    // ---- epilogue: 8 passes of 32 rows via LDS transpose (stride 260) ----
    float* cbuf = (float*)smem;            // 32*260*4 = 33.3KB < 64KB
    float4 bv4[4];
    const int er = tid >> 4;               // 0..31
    const int ec = (tid & 15) << 2;        // f32 col quad base
#pragma unroll
    for (int i = 0; i < 4; ++i)
        bv4[i] = *(const float4*)(bias + (g << 9) + n0 + ec + (i << 6));

#pragma unroll
    for (int pp = 0; pp < 8; ++pp) {
        if (wm == (pp >> 2)) {
#pragma unroll
            for (int m = 0; m < 2; ++m) {
                const int am = (pp & 3) * 2 + m;
#pragma unroll
                for (int ni = 0; ni < 4; ++ni) {
                    const int base = (m * 16 + kg * 4) * 260 + wn * 64 + ni * 16 + colf;
                    cbuf[base]       = acc[am][ni][0];
                    cbuf[base + 260] = acc[am][ni][1];
                    cbuf[base + 520] = acc[am][ni][2];
                    cbuf[base + 780] = acc[am][ni][3];
                }
            }
        }
        WAITL0;
        BARRIER;
        const int row = pp * 32 + er;
        if (row < vr) {
            float* orow = out + (((size_t)(batch * TTOT + t0 + row)) << 9) + n0;
#pragma unroll
            for (int i = 0; i < 4; ++i) {
                float4 v = *(const float4*)(cbuf + er * 260 + ec + (i << 6));
                float4 o4;
                o4.x = v.x + bv4[i].x; o4.y = v.y + bv4[i].y;
                o4.z = v.z + bv4[i].z; o4.w = v.w + bv4[i].w;
                *(float4*)(orow + ec + (i << 6)) = o4;
            }
        }
        BARRIER;   // protect cbuf before next pass overwrites
    }
#undef ISSUE_A
#undef CVT_WRITE_A
#undef ISSUE_B
#undef COMPUTE
#undef FENCE
#undef WAITV4
#undef WAITV0
#undef WAITL0
#undef BARRIER
}

// ---- Fallback (ws too small): R2-style 64x128 kernel, fp32 W path ----
__launch_bounds__(256)
__global__ void gemm_fallback(const float* __restrict__ x,
                              const float* __restrict__ W,
                              const float* __restrict__ bias,
                              float* __restrict__ out) {
    __shared__ __align__(16) char smem[49152];
    const int tid  = threadIdx.x;
    const int lane = tid & 63;
    const int wid  = tid >> 6;
    const int wm   = wid >> 1;
    const int wn   = wid & 1;
    const int p  = blockIdx.x;
    const int l  = ((p & 7) << 9) + (p >> 3);
    const int mt = l >> 2;
    const int nt = l & 3;
    const int bb = mt >> 6;
    const int t0 = (mt & 63) << 6;
    const int n0 = nt << 7;
    int g = 0;
    if (t0 >= 256)  g++; if (t0 >= 768)  g++; if (t0 >= 1536) g++;
    if (t0 >= 1920) g++; if (t0 >= 2560) g++; if (t0 >= 3072) g++;
    if (t0 >= 3648) g++;
    const int arow = tid >> 2;
    const int acol = (tid & 3) << 4;
    const float* aptr = x + ((size_t)(bb * TTOT + t0 + arow)) * DIN + acol;
    float4 a0, a1, a2, a3;
    float4 bw0[4], bw1[4];
    auto load_global = [&](int k0) {
        a0 = *(const float4*)(aptr + k0);
        a1 = *(const float4*)(aptr + k0 + 4);
        a2 = *(const float4*)(aptr + k0 + 8);
        a3 = *(const float4*)(aptr + k0 + 12);
#pragma unroll
        for (int pp = 0; pp < 4; ++pp) {
            int idx = pp * 256 + tid;
            int row = idx >> 3, seg = idx & 7;
            const float* wp = W + ((size_t)((g << 9) + n0 + row)) * DIN + k0 + (seg << 3);
            bw0[pp] = *(const float4*)(wp);
            bw1[pp] = *(const float4*)(wp + 4);
        }
    };
    auto swzf = [](int row, int bc) { return (row << 7) + (bc ^ ((row & 7) << 4)); };
    auto write_lds = [&](int buf) {
        char* ab  = smem + buf * 8192;
        char* bb_ = smem + 16384 + buf * 16384;
        s16x8 w0, w1;
        w0[0]=f2b(a0.x); w0[1]=f2b(a0.y); w0[2]=f2b(a0.z); w0[3]=f2b(a0.w);
        w0[4]=f2b(a1.x); w0[5]=f2b(a1.y); w0[6]=f2b(a1.z); w0[7]=f2b(a1.w);
        w1[0]=f2b(a2.x); w1[1]=f2b(a2.y); w1[2]=f2b(a2.z); w1[3]=f2b(a2.w);
        w1[4]=f2b(a3.x); w1[5]=f2b(a3.y); w1[6]=f2b(a3.z); w1[7]=f2b(a3.w);
        const int abase2 = acol << 1;
        *(s16x8*)(ab + swzf(arow, abase2))      = w0;
        *(s16x8*)(ab + swzf(arow, abase2 + 16)) = w1;
#pragma unroll
        for (int pp = 0; pp < 4; ++pp) {
            int idx = pp * 256 + tid;
            int row = idx >> 3, seg = idx & 7;
            s16x8 wvv;
            wvv[0]=f2b(bw0[pp].x); wvv[1]=f2b(bw0[pp].y);
            wvv[2]=f2b(bw0[pp].z); wvv[3]=f2b(bw0[pp].w);
            wvv[4]=f2b(bw1[pp].x); wvv[5]=f2b(bw1[pp].y);
            wvv[6]=f2b(bw1[pp].z); wvv[7]=f2b(bw1[pp].w);
            *(s16x8*)(bb_ + swzf(row, seg << 4)) = wvv;
        }
    };
    f32x4 acc[2][4];
#pragma unroll
    for (int mi = 0; mi < 2; ++mi)
#pragma unroll
        for (int ni = 0; ni < 4; ++ni) acc[mi][ni] = (f32x4){0.f,0.f,0.f,0.f};
    const int colf = lane & 15;
    const int kgrp = lane >> 4;
    auto compute = [&](int buf) {
        const char* ab  = smem + buf * 8192;
        const char* bb_ = smem + 16384 + buf * 16384;
#pragma unroll
        for (int ks = 0; ks < 2; ++ks) {
            const int kb = ks * 64 + kgrp * 16;
            s16x8 af[2], bf[4];
#pragma unroll
            for (int mi = 0; mi < 2; ++mi)
                af[mi] = *(const s16x8*)(ab + swzf(wm * 32 + mi * 16 + colf, kb));
#pragma unroll
            for (int ni = 0; ni < 4; ++ni)
                bf[ni] = *(const s16x8*)(bb_ + swzf(wn * 64 + ni * 16 + colf, kb));
#pragma unroll
            for (int mi = 0; mi < 2; ++mi)
#pragma unroll
                for (int ni = 0; ni < 4; ++ni)
                    acc[mi][ni] = __builtin_amdgcn_mfma_f32_16x16x32_bf16(
                        af[mi], bf[ni], acc[mi][ni], 0, 0, 0);
        }
    };
    load_global(0);
    write_lds(0);
    __syncthreads();
    int buf = 0;
#pragma unroll 1
    for (int kt = 0; kt < 8; ++kt) {
        if (kt < 7) load_global((kt + 1) << 6);
        compute(buf);
        if (kt < 7) write_lds(buf ^ 1);
        __syncthreads();
        buf ^= 1;
    }
    float* cbuf = (float*)smem;
#pragma unroll
    for (int ni = 0; ni < 4; ++ni) {
        const int c = wn * 64 + ni * 16 + colf;
#pragma unroll
        for (int mi = 0; mi < 2; ++mi) {
            const int rr2 = wm * 32 + mi * 16 + kgrp * 4;
            f32x4 v = acc[mi][ni];
            cbuf[(rr2 + 0) * 132 + c] = v[0];
            cbuf[(rr2 + 1) * 132 + c] = v[1];
            cbuf[(rr2 + 2) * 132 + c] = v[2];
            cbuf[(rr2 + 3) * 132 + c] = v[3];
        }
    }
    __syncthreads();
    const int rr = tid >> 5;
    const int cc = (tid & 31) << 2;
    const float4 bvv = *(const float4*)(bias + (g << 9) + n0 + cc);
#pragma unroll
    for (int it = 0; it < 8; ++it) {
        const int row = it * 8 + rr;
        float4 v = *(const float4*)(cbuf + row * 132 + cc);
        float4 o4; o4.x = v.x + bvv.x; o4.y = v.y + bvv.y;
                   o4.z = v.z + bvv.z; o4.w = v.w + bvv.w;
        *(float4*)(out + ((size_t)(bb * TTOT) + t0 + row) * DOUT + n0 + cc) = o4;
    }
}

extern "C" void kernel_launch(void* const* d_in, const int* in_sizes, int n_in,
                              void* d_out, int out_size, void* d_ws, size_t ws_size,
                              hipStream_t stream) {
    const float* x    = (const float*)d_in[0];
    const float* W    = (const float*)d_in[1];
    const float* bias = (const float*)d_in[2];
    float* out = (float*)d_out;

    const size_t wbytes = (size_t)NG * DOUT * DIN * sizeof(ushort);  // 4 MB

    if (ws_size >= wbytes) {
        ushort* wbf = (ushort*)d_ws;
        wconv_kernel<<<1024, 256, 0, stream>>>(W, wbf);
        gemm_kernel<<<NJB * BATCH * 2, 512, 0, stream>>>(x, wbf, bias, out);
    } else {
        gemm_fallback<<<BATCH * 64 * 4, 256, 0, stream>>>(x, W, bias, out);
    }
}

// Round 9
// 130.877 us; speedup vs baseline: 3.7765x; 3.7765x over previous
//
#include <hip/hip_runtime.h>
#include <hip/hip_bf16.h>
#include <cstdint>

#define BATCH 16
#define TTOT  4096
#define DIN   512
#define DOUT  512
#define NG    8
#define NJB   18

typedef float f32x4 __attribute__((ext_vector_type(4)));
typedef short s16x8 __attribute__((ext_vector_type(8)));

__device__ __forceinline__ short f2b(float f) {
    union { __bf16 b; short s; } u; u.b = (__bf16)f; return u.s;
}

// M-job tables (BM=256), verified in R7/R8.
__device__ __constant__ short JT0[NJB] = {
    0,256,512,768,1024,1280,1536,1792,1920,2176,2432,2560,2816,3072,3328,3584,3648,3904};
__device__ __constant__ char JG[NJB] = {
    0,1,1,2,2,2,3,3,4,4,4,5,5,6,6,6,7,7};
__device__ __constant__ short JVR[NJB] = {
    256,256,256,256,256,256,256,128,256,256,128,256,256,256,256,64,256,192};

// ---- Kernel 1: W fp32 -> bf16, pre-swizzled 128-row LDS-image chunks ----
// (verbatim R3/R5, measured conflict-free) chunk c = (g*4+nt)*8+kt, 16KB:
// chunk[row*128+bc] = bf16 W[g][nt*128+row][kt*64 + ((bc ^ ((row&7)<<4))>>1)]
__global__ void wconv_kernel(const float* __restrict__ W, ushort* __restrict__ wbf) {
    int gid = blockIdx.x * 256 + threadIdx.x;
    int c = gid >> 10;
    int q = (gid & 1023) << 4;
    int row = q >> 7;
    int bc  = q & 127;
    int kbyte = bc ^ ((row & 7) << 4);
    int kt = c & 7, nt = (c >> 3) & 3, g = c >> 5;
    const float* wp = W + ((size_t)(g * DOUT + nt * 128 + row)) * DIN
                        + kt * 64 + (kbyte >> 1);
    float4 v0 = *reinterpret_cast<const float4*>(wp);
    float4 v1 = *reinterpret_cast<const float4*>(wp + 4);
    s16x8 o;
    o[0]=f2b(v0.x); o[1]=f2b(v0.y); o[2]=f2b(v0.z); o[3]=f2b(v0.w);
    o[4]=f2b(v1.x); o[5]=f2b(v1.y); o[6]=f2b(v1.z); o[7]=f2b(v1.w);
    *reinterpret_cast<s16x8*>((char*)wbf + (size_t)c * 16384 + q) = o;
}

// ---- Kernel 2: 8-phase grouped GEMM 256x128x64, 8 waves (4Mx2N), wave 64x64.
// Per K-tile: 4 phases {ds_read ∥ 1 half-stage ∥ bar ∥ 8 MFMA ∥ bar}.
// vmcnt(8) only at phases 4/8. A: fixed reg pair, 4-phase lead. ----
__launch_bounds__(512, 2)
__global__ void gemm_kernel(const float* __restrict__ x,
                            const ushort* __restrict__ wbf,
                            const float* __restrict__ bias,
                            float* __restrict__ out) {
    // [A0 32K][A1 32K] @0 | [B0 16K][B1 16K] @65536 ; cbuf overlays A.
    __shared__ __align__(16) char smem[98304];

    const int tid  = threadIdx.x;
    const int lane = tid & 63;
    const int wv   = tid >> 6;      // 0..7
    const int wm   = wv >> 1;       // 0..3 : 64-row slab
    const int wn   = wv & 1;        // 0..1 : 64-col slab
    const int colf = lane & 15;
    const int kg   = lane >> 4;

    const int p    = blockIdx.x;                 // 0..1151
    const int l    = (p & 7) * 144 + (p >> 3);   // XCD-bijective
    const int nt   = l & 3;                      // nt fastest: A L2-reuse
    const int rest = l >> 2;                     // 0..287
    const int batch = rest / NJB;
    const int j     = rest - batch * NJB;
    const int t0    = JT0[j];
    const int g     = JG[j];
    const int vr    = JVR[j];
    const int n0    = nt << 7;

    const char* bchunk = (const char*)wbf + (size_t)((g * 4 + nt) * 8) * 16384;

    // A staging: thread -> half-row ar=tid>>2 (0..127), qq=tid&3 (16 f32 cols)
    const int ar = tid >> 2;
    const int qq = tid & 3;
    int r0 = ar;        if (r0 >= vr) r0 = vr - 1;
    int r1 = 128 + ar;  if (r1 >= vr) r1 = vr - 1;
    const float* aptr0 = x + ((size_t)(batch * TTOT + t0 + r0)) * DIN + (qq << 4);
    const float* aptr1 = x + ((size_t)(batch * TTOT + t0 + r1)) * DIN + (qq << 4);
    const int awo = (qq << 5) ^ ((ar & 7) << 4);   // swizzled byte col

    float4 pA0[4], pA1[4];
    s16x8 afr[4], bfr[2];
    f32x4 acc[4][4];
#pragma unroll
    for (int mi = 0; mi < 4; ++mi)
#pragma unroll
        for (int ni = 0; ni < 4; ++ni)
            acc[mi][ni] = (f32x4){0.f, 0.f, 0.f, 0.f};

#define SG_AISSUE(R_, P_, KT_) do {                                         \
        R_[0] = *(const float4*)((P_) + ((KT_) << 6));                      \
        R_[1] = *(const float4*)((P_) + ((KT_) << 6) + 4);                  \
        R_[2] = *(const float4*)((P_) + ((KT_) << 6) + 8);                  \
        R_[3] = *(const float4*)((P_) + ((KT_) << 6) + 12);                 \
    } while (0)

#define SG_AWRITE(R_, HALF_, SLOT_) do {                                    \
        char* ab_ = smem + (SLOT_) * 32768 + (((HALF_) * 128 + ar) << 7);   \
        s16x8 o0_, o1_;                                                     \
        o0_[0]=f2b(R_[0].x); o0_[1]=f2b(R_[0].y); o0_[2]=f2b(R_[0].z); o0_[3]=f2b(R_[0].w); \
        o0_[4]=f2b(R_[1].x); o0_[5]=f2b(R_[1].y); o0_[6]=f2b(R_[1].z); o0_[7]=f2b(R_[1].w); \
        o1_[0]=f2b(R_[2].x); o1_[1]=f2b(R_[2].y); o1_[2]=f2b(R_[2].z); o1_[3]=f2b(R_[2].w); \
        o1_[4]=f2b(R_[3].x); o1_[5]=f2b(R_[3].y); o1_[6]=f2b(R_[3].z); o1_[7]=f2b(R_[3].w); \
        *(s16x8*)(ab_ + awo)        = o0_;                                  \
        *(s16x8*)(ab_ + (awo ^ 16)) = o1_;                                  \
    } while (0)

#define SG_B(HALF_, KT_, SLOT_) do {                                        \
        const char* s_ = bchunk + (size_t)(KT_) * 16384 + (HALF_) * 8192 + tid * 16; \
        char* d_ = smem + 65536 + (SLOT_) * 16384 + (HALF_) * 8192 + tid * 16; \
        __builtin_amdgcn_global_load_lds(                                   \
            (const __attribute__((address_space(1))) void*)s_,              \
            (__attribute__((address_space(3))) void*)d_, 16, 0, 0);         \
    } while (0)

#define DSR_A(SLOT_, KS_) do {                                              \
        const char* ab_ = smem + (SLOT_) * 32768;                           \
        _Pragma("unroll")                                                   \
        for (int mi = 0; mi < 4; ++mi) {                                    \
            int rr_ = wm * 64 + mi * 16 + colf;                             \
            afr[mi] = *(const s16x8*)(ab_ + (rr_ << 7)                      \
                        + (((KS_) * 64 + (kg << 4)) ^ ((rr_ & 7) << 4)));   \
        }                                                                   \
    } while (0)

#define DSR_B(SLOT_, KS_, NP_) do {                                         \
        const char* bb_ = smem + 65536 + (SLOT_) * 16384;                   \
        _Pragma("unroll")                                                   \
        for (int nj = 0; nj < 2; ++nj) {                                    \
            int rr_ = wn * 64 + ((NP_) * 2 + nj) * 16 + colf;               \
            bfr[nj] = *(const s16x8*)(bb_ + (rr_ << 7)                      \
                        + (((KS_) * 64 + (kg << 4)) ^ ((rr_ & 7) << 4)));   \
        }                                                                   \
    } while (0)

#define MFMA8(NP_) do {                                                     \
        __builtin_amdgcn_s_setprio(1);                                      \
        _Pragma("unroll")                                                   \
        for (int mi = 0; mi < 4; ++mi)                                      \
            _Pragma("unroll")                                               \
            for (int nj = 0; nj < 2; ++nj)                                  \
                acc[mi][(NP_) * 2 + nj] = __builtin_amdgcn_mfma_f32_16x16x32_bf16( \
                    afr[mi], bfr[nj], acc[mi][(NP_) * 2 + nj], 0, 0, 0);    \
        __builtin_amdgcn_s_setprio(0);                                      \
    } while (0)

#define LGKM0_SB do { asm volatile("s_waitcnt lgkmcnt(0)" ::: "memory");    \
                      __builtin_amdgcn_sched_barrier(0); } while (0)
#define BAR    __builtin_amdgcn_s_barrier()
#define WAITV8 asm volatile("s_waitcnt vmcnt(8)" ::: "memory")
#define WAITV0 asm volatile("s_waitcnt vmcnt(0)" ::: "memory")

// One main iteration: consume tile 2i (slot0, P1-4) and 2i+1 (slot1, P5-8).
// Stage tile KT1_=2i+1 into slot1 (P1-P4) and KT2_=2i+2 into slot0 (P5-P8);
// issue A-reg loads for KT2_ (P3,P4) and KT3_=2i+3 (P7,P8).
#define ITER(KT1_, KT2_, KT3_, HAS2_, HAS3_) do {                           \
    /*P1*/ DSR_A(0,0); DSR_B(0,0,0); SG_B(0, KT1_, 1); BAR; MFMA8(0); BAR;  \
    /*P2*/ DSR_B(0,0,1); SG_B(1, KT1_, 1); BAR; MFMA8(1); BAR;              \
    /*P3*/ SG_AWRITE(pA0, 0, 1); if (HAS2_) SG_AISSUE(pA0, aptr0, KT2_);    \
           DSR_A(0,1); DSR_B(0,1,0); LGKM0_SB; BAR; MFMA8(0); BAR;          \
    /*P4*/ SG_AWRITE(pA1, 1, 1); if (HAS2_) SG_AISSUE(pA1, aptr1, KT2_);    \
           DSR_B(0,1,1); LGKM0_SB; BAR; MFMA8(1);                           \
           if (HAS2_) { WAITV8; } else { WAITV0; } BAR;                     \
    /*P5*/ DSR_A(1,0); DSR_B(1,0,0); if (HAS2_) SG_B(0, KT2_, 0); BAR; MFMA8(0); BAR; \
    /*P6*/ DSR_B(1,0,1); if (HAS2_) SG_B(1, KT2_, 0); BAR; MFMA8(1); BAR;   \
    /*P7*/ if (HAS2_) { SG_AWRITE(pA0, 0, 0); }                             \
           if (HAS3_) SG_AISSUE(pA0, aptr0, KT3_);                          \
           DSR_A(1,1); DSR_B(1,1,0); LGKM0_SB; BAR; MFMA8(0); BAR;          \
    /*P8*/ if (HAS2_) { SG_AWRITE(pA1, 1, 0); }                             \
           if (HAS3_) SG_AISSUE(pA1, aptr1, KT3_);                          \
           DSR_B(1,1,1); LGKM0_SB; BAR; MFMA8(1);                           \
           if (HAS2_) { if (HAS3_) { WAITV8; } else { WAITV0; } } BAR;      \
} while (0)

    // ---- prologue: tile0 -> slot0; pA <- A(tile1) ----
    SG_AISSUE(pA0, aptr0, 0);
    SG_AISSUE(pA1, aptr1, 0);
    SG_B(0, 0, 0); SG_B(1, 0, 0);
    SG_AWRITE(pA0, 0, 0);                    // reg-dep waits A0(t0), keeps 6 in flight
    SG_AISSUE(pA0, aptr0, 1);
    SG_AWRITE(pA1, 1, 0);
    SG_AISSUE(pA1, aptr1, 1);
    WAITV8;                                  // B(t0) landed; A(t1) 8 ride
    LGKM0_SB;
    BAR;

    ITER(1, 2, 3, 1, 1);
    ITER(3, 4, 5, 1, 1);
    ITER(5, 6, 7, 1, 1);
    ITER(7, 8, 9, 0, 0);

    // ---- epilogue: 8 passes of 32 rows via LDS transpose (stride 132) ----
    float* cbuf = (float*)smem;
    const int er = tid >> 4;               // 0..31
    const int ec = (tid & 15) << 3;        // 0..120
    float4 bvA = *(const float4*)(bias + (g << 9) + n0 + ec);
    float4 bvB = *(const float4*)(bias + (g << 9) + n0 + ec + 4);

#pragma unroll
    for (int pp = 0; pp < 8; ++pp) {
        if (wm == (pp >> 1)) {
#pragma unroll
            for (int m = 0; m < 2; ++m) {
                const int mi = (pp & 1) * 2 + m;
#pragma unroll
                for (int ni = 0; ni < 4; ++ni) {
                    const int base = (m * 16 + kg * 4) * 132 + wn * 64 + ni * 16 + colf;
                    cbuf[base]       = acc[mi][ni][0];
                    cbuf[base + 132] = acc[mi][ni][1];
                    cbuf[base + 264] = acc[mi][ni][2];
                    cbuf[base + 396] = acc[mi][ni][3];
                }
            }
        }
        asm volatile("s_waitcnt lgkmcnt(0)" ::: "memory");
        BAR;
        const int row = pp * 32 + er;
        if (row < vr) {
            float* orow = out + ((size_t)(batch * TTOT + t0 + row)) * DOUT + n0 + ec;
            float4 v0 = *(const float4*)(cbuf + er * 132 + ec);
            float4 v1 = *(const float4*)(cbuf + er * 132 + ec + 4);
            float4 o0, o1;
            o0.x = v0.x + bvA.x; o0.y = v0.y + bvA.y;
            o0.z = v0.z + bvA.z; o0.w = v0.w + bvA.w;
            o1.x = v1.x + bvB.x; o1.y = v1.y + bvB.y;
            o1.z = v1.z + bvB.z; o1.w = v1.w + bvB.w;
            *(float4*)(orow)     = o0;
            *(float4*)(orow + 4) = o1;
        }
        BAR;
    }
#undef SG_AISSUE
#undef SG_AWRITE
#undef SG_B
#undef DSR_A
#undef DSR_B
#undef MFMA8
#undef LGKM0_SB
#undef BAR
#undef WAITV8
#undef WAITV0
#undef ITER
}

// ---- Fallback (ws too small): R2-style 64x128 kernel, fp32 W path ----
__launch_bounds__(256)
__global__ void gemm_fallback(const float* __restrict__ x,
                              const float* __restrict__ W,
                              const float* __restrict__ bias,
                              float* __restrict__ out) {
    __shared__ __align__(16) char smem[49152];
    const int tid  = threadIdx.x;
    const int lane = tid & 63;
    const int wid  = tid >> 6;
    const int wm   = wid >> 1;
    const int wn   = wid & 1;
    const int p  = blockIdx.x;
    const int l  = ((p & 7) << 9) + (p >> 3);
    const int mt = l >> 2;
    const int nt = l & 3;
    const int bb = mt >> 6;
    const int t0 = (mt & 63) << 6;
    const int n0 = nt << 7;
    int g = 0;
    if (t0 >= 256)  g++; if (t0 >= 768)  g++; if (t0 >= 1536) g++;
    if (t0 >= 1920) g++; if (t0 >= 2560) g++; if (t0 >= 3072) g++;
    if (t0 >= 3648) g++;
    const int arow = tid >> 2;
    const int acol = (tid & 3) << 4;
    const float* aptr = x + ((size_t)(bb * TTOT + t0 + arow)) * DIN + acol;
    float4 a0, a1, a2, a3;
    float4 bw0[4], bw1[4];
    auto load_global = [&](int k0) {
        a0 = *(const float4*)(aptr + k0);
        a1 = *(const float4*)(aptr + k0 + 4);
        a2 = *(const float4*)(aptr + k0 + 8);
        a3 = *(const float4*)(aptr + k0 + 12);
#pragma unroll
        for (int pp = 0; pp < 4; ++pp) {
            int idx = pp * 256 + tid;
            int row = idx >> 3, seg = idx & 7;
            const float* wp = W + ((size_t)((g << 9) + n0 + row)) * DIN + k0 + (seg << 3);
            bw0[pp] = *(const float4*)(wp);
            bw1[pp] = *(const float4*)(wp + 4);
        }
    };
    auto swzf = [](int row, int bc) { return (row << 7) + (bc ^ ((row & 7) << 4)); };
    auto write_lds = [&](int buf) {
        char* ab  = smem + buf * 8192;
        char* bb_ = smem + 16384 + buf * 16384;
        s16x8 w0, w1;
        w0[0]=f2b(a0.x); w0[1]=f2b(a0.y); w0[2]=f2b(a0.z); w0[3]=f2b(a0.w);
        w0[4]=f2b(a1.x); w0[5]=f2b(a1.y); w0[6]=f2b(a1.z); w0[7]=f2b(a1.w);
        w1[0]=f2b(a2.x); w1[1]=f2b(a2.y); w1[2]=f2b(a2.z); w1[3]=f2b(a2.w);
        w1[4]=f2b(a3.x); w1[5]=f2b(a3.y); w1[6]=f2b(a3.z); w1[7]=f2b(a3.w);
        const int abase2 = acol << 1;
        *(s16x8*)(ab + swzf(arow, abase2))      = w0;
        *(s16x8*)(ab + swzf(arow, abase2 + 16)) = w1;
#pragma unroll
        for (int pp = 0; pp < 4; ++pp) {
            int idx = pp * 256 + tid;
            int row = idx >> 3, seg = idx & 7;
            s16x8 wvv;
            wvv[0]=f2b(bw0[pp].x); wvv[1]=f2b(bw0[pp].y);
            wvv[2]=f2b(bw0[pp].z); wvv[3]=f2b(bw0[pp].w);
            wvv[4]=f2b(bw1[pp].x); wvv[5]=f2b(bw1[pp].y);
            wvv[6]=f2b(bw1[pp].z); wvv[7]=f2b(bw1[pp].w);
            *(s16x8*)(bb_ + swzf(row, seg << 4)) = wvv;
        }
    };
    f32x4 acc[2][4];
#pragma unroll
    for (int mi = 0; mi < 2; ++mi)
#pragma unroll
        for (int ni = 0; ni < 4; ++ni) acc[mi][ni] = (f32x4){0.f,0.f,0.f,0.f};
    const int colf = lane & 15;
    const int kgrp = lane >> 4;
    auto compute = [&](int buf) {
        const char* ab  = smem + buf * 8192;
        const char* bb_ = smem + 16384 + buf * 16384;
#pragma unroll
        for (int ks = 0; ks < 2; ++ks) {
            const int kb = ks * 64 + kgrp * 16;
            s16x8 af[2], bf[4];
#pragma unroll
            for (int mi = 0; mi < 2; ++mi)
                af[mi] = *(const s16x8*)(ab + swzf(wm * 32 + mi * 16 + colf, kb));
#pragma unroll
            for (int ni = 0; ni < 4; ++ni)
                bf[ni] = *(const s16x8*)(bb_ + swzf(wn * 64 + ni * 16 + colf, kb));
#pragma unroll
            for (int mi = 0; mi < 2; ++mi)
#pragma unroll
                for (int ni = 0; ni < 4; ++ni)
                    acc[mi][ni] = __builtin_amdgcn_mfma_f32_16x16x32_bf16(
                        af[mi], bf[ni], acc[mi][ni], 0, 0, 0);
        }
    };
    load_global(0);
    write_lds(0);
    __syncthreads();
    int buf = 0;
#pragma unroll 1
    for (int kt = 0; kt < 8; ++kt) {
        if (kt < 7) load_global((kt + 1) << 6);
        compute(buf);
        if (kt < 7) write_lds(buf ^ 1);
        __syncthreads();
        buf ^= 1;
    }
    float* cbuf = (float*)smem;
#pragma unroll
    for (int ni = 0; ni < 4; ++ni) {
        const int c = wn * 64 + ni * 16 + colf;
#pragma unroll
        for (int mi = 0; mi < 2; ++mi) {
            const int rr2 = wm * 32 + mi * 16 + kgrp * 4;
            f32x4 v = acc[mi][ni];
            cbuf[(rr2 + 0) * 132 + c] = v[0];
            cbuf[(rr2 + 1) * 132 + c] = v[1];
            cbuf[(rr2 + 2) * 132 + c] = v[2];
            cbuf[(rr2 + 3) * 132 + c] = v[3];
        }
    }
    __syncthreads();
    const int rr = tid >> 5;
    const int cc = (tid & 31) << 2;
    const float4 bvv = *(const float4*)(bias + (g << 9) + n0 + cc);
#pragma unroll
    for (int it = 0; it < 8; ++it) {
        const int row = it * 8 + rr;
        float4 v = *(const float4*)(cbuf + row * 132 + cc);
        float4 o4; o4.x = v.x + bvv.x; o4.y = v.y + bvv.y;
                   o4.z = v.z + bvv.z; o4.w = v.w + bvv.w;
        *(float4*)(out + ((size_t)(bb * TTOT) + t0 + row) * DOUT + n0 + cc) = o4;
    }
}

extern "C" void kernel_launch(void* const* d_in, const int* in_sizes, int n_in,
                              void* d_out, int out_size, void* d_ws, size_t ws_size,
                              hipStream_t stream) {
    const float* x    = (const float*)d_in[0];
    const float* W    = (const float*)d_in[1];
    const float* bias = (const float*)d_in[2];
    float* out = (float*)d_out;

    const size_t wbytes = (size_t)NG * DOUT * DIN * sizeof(ushort);  // 4 MB

    if (ws_size >= wbytes) {
        ushort* wbf = (ushort*)d_ws;
        wconv_kernel<<<1024, 256, 0, stream>>>(W, wbf);
        gemm_kernel<<<NJB * BATCH * 4, 512, 0, stream>>>(x, wbf, bias, out);
    } else {
        gemm_fallback<<<BATCH * 64 * 4, 256, 0, stream>>>(x, W, bias, out);
    }
}

// Round 10
// 116.516 us; speedup vs baseline: 4.2419x; 1.1233x over previous
//
#include <hip/hip_runtime.h>
#include <hip/hip_bf16.h>
#include <cstdint>

#define BATCH 16
#define TTOT  4096
#define DIN   512
#define DOUT  512
#define NG    8
#define NKT   8      // K tiles of 64

typedef float f32x4 __attribute__((ext_vector_type(4)));
typedef short s16x8 __attribute__((ext_vector_type(8)));

__device__ __forceinline__ short f2b(float f) {
    union { __bf16 b; short s; } u; u.b = (__bf16)f; return u.s;
}

// ---- Kernel 1: W fp32 -> bf16, pre-swizzled FULL-N LDS-image chunks ----
// chunk c = g*8+kt (64 KB): img[row<512][bc<128] =
//   bf16 W[g][row][kt*64 + ((bc ^ ((row&7)<<4))>>1)]
__global__ void wconv_kernel(const float* __restrict__ W, ushort* __restrict__ wbf) {
    int gid = blockIdx.x * 256 + threadIdx.x;    // 262144 granules x 16B
    int c = gid >> 12;                           // 0..63
    int q = (gid & 4095) << 4;                   // byte in 64KB chunk
    int row = q >> 7;                            // 0..511
    int bc  = q & 127;
    int k = ((c & 7) << 6) + ((bc ^ ((row & 7) << 4)) >> 1);
    int g = c >> 3;
    const float* wp = W + ((size_t)((g << 9) + row) << 9) + k;
    float4 v0 = *reinterpret_cast<const float4*>(wp);
    float4 v1 = *reinterpret_cast<const float4*>(wp + 4);
    s16x8 o;
    o[0]=f2b(v0.x); o[1]=f2b(v0.y); o[2]=f2b(v0.z); o[3]=f2b(v0.w);
    o[4]=f2b(v1.x); o[5]=f2b(v1.y); o[6]=f2b(v1.z); o[7]=f2b(v1.w);
    *reinterpret_cast<s16x8*>((char*)wbf + (size_t)c * 65536 + q) = o;
}

// ---- Kernel 2: grouped GEMM 64x512x64 per block. 8 waves, wave-tile 64x64.
// x rows read from HBM exactly once (BN = full DOUT). B = full W K-slab via
// global_load_lds (L2-resident). A: 2 float4/thread reg ring, fused cvt.
// One barrier per K-tile; counted vmcnt(2). Grid 1024 = 4 rounds x 256 CU. ----
__launch_bounds__(512, 2)
__global__ void gemm_kernel(const float* __restrict__ x,
                            const ushort* __restrict__ wbf,
                            const float* __restrict__ bias,
                            float* __restrict__ out) {
    // [A0 8K][A1 8K] @0 | [B0 64K][B1 64K] @16K ; cbuf (64x516 f32) overlays.
    __shared__ __align__(16) char smem[147456];

    const int tid  = threadIdx.x;
    const int lane = tid & 63;
    const int wv   = tid >> 6;      // 0..7 : 64-col slab owner
    const int colf = lane & 15;
    const int kg   = lane >> 4;

    const int p  = blockIdx.x;                // 0..1023
    const int l  = ((p & 7) << 7) + (p >> 3); // XCD-bijective (1024 = 8*128)
    const int mt = l >> 4;                    // 0..63  (m-tile, 64 rows)
    const int batch = l & 15;
    const int t0 = mt << 6;
    int g = 0;
    if (mt >= 4)  g++; if (mt >= 12) g++; if (mt >= 24) g++;
    if (mt >= 30) g++; if (mt >= 40) g++; if (mt >= 48) g++;
    if (mt >= 57) g++;

    const char* bchunk = (const char*)wbf + (size_t)(g << 3) * 65536;

    // A staging: thread -> row arow = tid>>3 (0..63); source k pre-XORed so the
    // linear LDS image [row][bc] matches the B image convention.
    const int arow = tid >> 3;
    const int koff = ((tid & 7) ^ (arow & 7)) << 3;          // 8 fp32
    const float* aptr = x + ((size_t)((batch << 12) + t0 + arow) << 9) + koff;
    const int awb = (arow << 7) + ((tid & 7) << 4);          // LDS byte dst

    float4 aE[2], aO[2];
    f32x4 acc[4][4];
#pragma unroll
    for (int mi = 0; mi < 4; ++mi)
#pragma unroll
        for (int ni = 0; ni < 4; ++ni)
            acc[mi][ni] = (f32x4){0.f, 0.f, 0.f, 0.f};

#define ISSUE_A(S, KT_) do {                                                \
        const float* p_ = aptr + ((KT_) << 6);                              \
        a##S[0] = *(const float4*)(p_);                                     \
        a##S[1] = *(const float4*)(p_ + 4);                                 \
    } while (0)

#define CVT_WRITE_A(S, KT_) do {                                            \
        s16x8 o_;                                                           \
        o_[0]=f2b(a##S[0].x); o_[1]=f2b(a##S[0].y);                         \
        o_[2]=f2b(a##S[0].z); o_[3]=f2b(a##S[0].w);                         \
        o_[4]=f2b(a##S[1].x); o_[5]=f2b(a##S[1].y);                         \
        o_[6]=f2b(a##S[1].z); o_[7]=f2b(a##S[1].w);                         \
        *(s16x8*)(smem + (((KT_) & 1) << 13) + awb) = o_;                   \
    } while (0)

#define ISSUE_B(KT_) do {                                                   \
        const char* s_ = bchunk + ((size_t)(KT_) << 16) + tid * 16;         \
        char* d_ = smem + 16384 + (((KT_) & 1) << 16) + tid * 16;           \
        _Pragma("unroll")                                                   \
        for (int i_ = 0; i_ < 8; ++i_) {                                    \
            __builtin_amdgcn_global_load_lds(                               \
                (const __attribute__((address_space(1))) void*)(s_ + i_ * 8192), \
                (__attribute__((address_space(3))) void*)(d_ + i_ * 8192),  \
                16, 0, 0);                                                  \
        }                                                                   \
    } while (0)

#define COMPUTE(KT_) do {                                                   \
        const char* ab_ = smem + (((KT_) & 1) << 13);                       \
        const char* bb_ = smem + 16384 + (((KT_) & 1) << 16);               \
        _Pragma("unroll")                                                   \
        for (int ks = 0; ks < 2; ++ks) {                                    \
            const int kb = ks * 64 + (kg << 4);                             \
            s16x8 af[4], bf[4];                                             \
            _Pragma("unroll")                                               \
            for (int mi = 0; mi < 4; ++mi) {                                \
                int r_ = mi * 16 + colf;                                    \
                af[mi] = *(const s16x8*)(ab_ + (r_ << 7) + (kb ^ ((r_ & 7) << 4))); \
            }                                                               \
            _Pragma("unroll")                                               \
            for (int ni = 0; ni < 4; ++ni) {                                \
                int r_ = (wv << 6) + ni * 16 + colf;                        \
                bf[ni] = *(const s16x8*)(bb_ + (r_ << 7) + (kb ^ ((r_ & 7) << 4))); \
            }                                                               \
            _Pragma("unroll")                                               \
            for (int mi = 0; mi < 4; ++mi)                                  \
                _Pragma("unroll")                                           \
                for (int ni = 0; ni < 4; ++ni)                              \
                    acc[mi][ni] = __builtin_amdgcn_mfma_f32_16x16x32_bf16(  \
                        af[mi], bf[ni], acc[mi][ni], 0, 0, 0);              \
        }                                                                   \
    } while (0)

#define FENCE  asm volatile("" ::: "memory")
#define WAITV2 asm volatile("s_waitcnt vmcnt(2)" ::: "memory")
#define WAITV0 asm volatile("s_waitcnt vmcnt(0)" ::: "memory")
#define WAITL0 asm volatile("s_waitcnt lgkmcnt(0)" ::: "memory")
#define BAR    __builtin_amdgcn_s_barrier()

    // ---- prologue: B(0)+A(0) staged; A(1) regs in flight ----
    ISSUE_A(E, 0);
    FENCE;
    ISSUE_B(0);
    FENCE;
    ISSUE_A(O, 1);
    FENCE;
    CVT_WRITE_A(E, 0);   // reg-dep waits A(0); B(0)x8 + A(1)x2 stay in flight
    WAITV2;              // B(0) landed; A(1) rides
    WAITL0;
    BAR;

#pragma unroll
    for (int kt = 0; kt < NKT; ++kt) {
        if (kt + 1 < NKT) { ISSUE_B(kt + 1); FENCE; }
        if (kt + 2 < NKT) {
            if (((kt + 2) & 1) == 0) { ISSUE_A(E, kt + 2); }
            else                     { ISSUE_A(O, kt + 2); }
            FENCE;
        }
        COMPUTE(kt);
        if (kt + 1 < NKT) {
            if (((kt + 1) & 1) == 0) { CVT_WRITE_A(E, kt + 1); }
            else                     { CVT_WRITE_A(O, kt + 1); }
            if (kt + 2 < NKT) { WAITV2; }   // B(kt+1) landed; A(kt+2) rides
            else              { WAITV0; }   // kt==6: only B(7) outstanding
            WAITL0;
            BAR;
        }
    }
    BAR;   // all waves done reading LDS before cbuf overlay

    // ---- epilogue: one-pass LDS transpose (64 x 516 f32 = 132KB) ----
    float* cbuf = (float*)smem;
#pragma unroll
    for (int mi = 0; mi < 4; ++mi)
#pragma unroll
        for (int ni = 0; ni < 4; ++ni) {
            const int r0 = mi * 16 + kg * 4;
            const int c  = (wv << 6) + ni * 16 + colf;
            f32x4 v = acc[mi][ni];
            cbuf[(r0 + 0) * 516 + c] = v[0];
            cbuf[(r0 + 1) * 516 + c] = v[1];
            cbuf[(r0 + 2) * 516 + c] = v[2];
            cbuf[(r0 + 3) * 516 + c] = v[3];
        }
    WAITL0;
    BAR;

    const int rr = tid >> 3;             // 0..63
    const int c0 = (tid & 7) << 6;       // 64-f32 chunk
    float* orow = out + ((size_t)((batch << 12) + t0 + rr) << 9) + c0;
    const float* crow = cbuf + rr * 516 + c0;
    const float* brow = bias + (g << 9) + c0;
#pragma unroll
    for (int i = 0; i < 16; ++i) {
        float4 v  = *(const float4*)(crow + (i << 2));
        float4 bv = *(const float4*)(brow + (i << 2));
        float4 o4;
        o4.x = v.x + bv.x; o4.y = v.y + bv.y;
        o4.z = v.z + bv.z; o4.w = v.w + bv.w;
        *(float4*)(orow + (i << 2)) = o4;
    }
#undef ISSUE_A
#undef CVT_WRITE_A
#undef ISSUE_B
#undef COMPUTE
#undef FENCE
#undef WAITV2
#undef WAITV0
#undef WAITL0
#undef BAR
}

// ---- Fallback (ws too small): R2-style 64x128 kernel, fp32 W path ----
__launch_bounds__(256)
__global__ void gemm_fallback(const float* __restrict__ x,
                              const float* __restrict__ W,
                              const float* __restrict__ bias,
                              float* __restrict__ out) {
    __shared__ __align__(16) char smem[49152];
    const int tid  = threadIdx.x;
    const int lane = tid & 63;
    const int wid  = tid >> 6;
    const int wm   = wid >> 1;
    const int wn   = wid & 1;
    const int p  = blockIdx.x;
    const int l  = ((p & 7) << 9) + (p >> 3);
    const int mt = l >> 2;
    const int nt = l & 3;
    const int bb = mt >> 6;
    const int t0 = (mt & 63) << 6;
    const int n0 = nt << 7;
    int g = 0;
    if (t0 >= 256)  g++; if (t0 >= 768)  g++; if (t0 >= 1536) g++;
    if (t0 >= 1920) g++; if (t0 >= 2560) g++; if (t0 >= 3072) g++;
    if (t0 >= 3648) g++;
    const int arow = tid >> 2;
    const int acol = (tid & 3) << 4;
    const float* aptr = x + ((size_t)(bb * TTOT + t0 + arow)) * DIN + acol;
    float4 a0, a1, a2, a3;
    float4 bw0[4], bw1[4];
    auto load_global = [&](int k0) {
        a0 = *(const float4*)(aptr + k0);
        a1 = *(const float4*)(aptr + k0 + 4);
        a2 = *(const float4*)(aptr + k0 + 8);
        a3 = *(const float4*)(aptr + k0 + 12);
#pragma unroll
        for (int pp = 0; pp < 4; ++pp) {
            int idx = pp * 256 + tid;
            int row = idx >> 3, seg = idx & 7;
            const float* wp = W + ((size_t)((g << 9) + n0 + row)) * DIN + k0 + (seg << 3);
            bw0[pp] = *(const float4*)(wp);
            bw1[pp] = *(const float4*)(wp + 4);
        }
    };
    auto swzf = [](int row, int bc) { return (row << 7) + (bc ^ ((row & 7) << 4)); };
    auto write_lds = [&](int buf) {
        char* ab  = smem + buf * 8192;
        char* bb_ = smem + 16384 + buf * 16384;
        s16x8 w0, w1;
        w0[0]=f2b(a0.x); w0[1]=f2b(a0.y); w0[2]=f2b(a0.z); w0[3]=f2b(a0.w);
        w0[4]=f2b(a1.x); w0[5]=f2b(a1.y); w0[6]=f2b(a1.z); w0[7]=f2b(a1.w);
        w1[0]=f2b(a2.x); w1[1]=f2b(a2.y); w1[2]=f2b(a2.z); w1[3]=f2b(a2.w);
        w1[4]=f2b(a3.x); w1[5]=f2b(a3.y); w1[6]=f2b(a3.z); w1[7]=f2b(a3.w);
        const int abase2 = acol << 1;
        *(s16x8*)(ab + swzf(arow, abase2))      = w0;
        *(s16x8*)(ab + swzf(arow, abase2 + 16)) = w1;
#pragma unroll
        for (int pp = 0; pp < 4; ++pp) {
            int idx = pp * 256 + tid;
            int row = idx >> 3, seg = idx & 7;
            s16x8 wvv;
            wvv[0]=f2b(bw0[pp].x); wvv[1]=f2b(bw0[pp].y);
            wvv[2]=f2b(bw0[pp].z); wvv[3]=f2b(bw0[pp].w);
            wvv[4]=f2b(bw1[pp].x); wvv[5]=f2b(bw1[pp].y);
            wvv[6]=f2b(bw1[pp].z); wvv[7]=f2b(bw1[pp].w);
            *(s16x8*)(bb_ + swzf(row, seg << 4)) = wvv;
        }
    };
    f32x4 acc[2][4];
#pragma unroll
    for (int mi = 0; mi < 2; ++mi)
#pragma unroll
        for (int ni = 0; ni < 4; ++ni) acc[mi][ni] = (f32x4){0.f,0.f,0.f,0.f};
    const int colf = lane & 15;
    const int kgrp = lane >> 4;
    auto compute = [&](int buf) {
        const char* ab  = smem + buf * 8192;
        const char* bb_ = smem + 16384 + buf * 16384;
#pragma unroll
        for (int ks = 0; ks < 2; ++ks) {
            const int kb = ks * 64 + kgrp * 16;
            s16x8 af[2], bf[4];
#pragma unroll
            for (int mi = 0; mi < 2; ++mi)
                af[mi] = *(const s16x8*)(ab + swzf(wm * 32 + mi * 16 + colf, kb));
#pragma unroll
            for (int ni = 0; ni < 4; ++ni)
                bf[ni] = *(const s16x8*)(bb_ + swzf(wn * 64 + ni * 16 + colf, kb));
#pragma unroll
            for (int mi = 0; mi < 2; ++mi)
#pragma unroll
                for (int ni = 0; ni < 4; ++ni)
                    acc[mi][ni] = __builtin_amdgcn_mfma_f32_16x16x32_bf16(
                        af[mi], bf[ni], acc[mi][ni], 0, 0, 0);
        }
    };
    load_global(0);
    write_lds(0);
    __syncthreads();
    int buf = 0;
#pragma unroll 1
    for (int kt = 0; kt < 8; ++kt) {
        if (kt < 7) load_global((kt + 1) << 6);
        compute(buf);
        if (kt < 7) write_lds(buf ^ 1);
        __syncthreads();
        buf ^= 1;
    }
    float* cbuf = (float*)smem;
#pragma unroll
    for (int ni = 0; ni < 4; ++ni) {
        const int c = wn * 64 + ni * 16 + colf;
#pragma unroll
        for (int mi = 0; mi < 2; ++mi) {
            const int rr2 = wm * 32 + mi * 16 + kgrp * 4;
            f32x4 v = acc[mi][ni];
            cbuf[(rr2 + 0) * 132 + c] = v[0];
            cbuf[(rr2 + 1) * 132 + c] = v[1];
            cbuf[(rr2 + 2) * 132 + c] = v[2];
            cbuf[(rr2 + 3) * 132 + c] = v[3];
        }
    }
    __syncthreads();
    const int rr = tid >> 5;
    const int cc = (tid & 31) << 2;
    const float4 bvv = *(const float4*)(bias + (g << 9) + n0 + cc);
#pragma unroll
    for (int it = 0; it < 8; ++it) {
        const int row = it * 8 + rr;
        float4 v = *(const float4*)(cbuf + row * 132 + cc);
        float4 o4; o4.x = v.x + bvv.x; o4.y = v.y + bvv.y;
                   o4.z = v.z + bvv.z; o4.w = v.w + bvv.w;
        *(float4*)(out + ((size_t)(bb * TTOT) + t0 + row) * DOUT + n0 + cc) = o4;
    }
}

extern "C" void kernel_launch(void* const* d_in, const int* in_sizes, int n_in,
                              void* d_out, int out_size, void* d_ws, size_t ws_size,
                              hipStream_t stream) {
    const float* x    = (const float*)d_in[0];
    const float* W    = (const float*)d_in[1];
    const float* bias = (const float*)d_in[2];
    float* out = (float*)d_out;

    const size_t wbytes = (size_t)NG * DOUT * DIN * sizeof(ushort);  // 4 MB

    if (ws_size >= wbytes) {
        ushort* wbf = (ushort*)d_ws;
        wconv_kernel<<<1024, 256, 0, stream>>>(W, wbf);
        gemm_kernel<<<1024, 512, 0, stream>>>(x, wbf, bias, out);
    } else {
        gemm_fallback<<<BATCH * 64 * 4, 256, 0, stream>>>(x, W, bias, out);
    }
}